// Round 4
// baseline (1251.311 us; speedup 1.0000x reference)
//
#include <hip/hip_runtime.h>
#include <hip/hip_cooperative_groups.h>
#include <cstdint>
#include <cstddef>

namespace cg = cooperative_groups;

// Problem constants
constexpr int B = 64, S = 2048, H = 512, E = 256, V = 32000;
constexpr int NCHUNK = 64;          // 32-key chunks per batch
constexpr int GRID = 512, BLK = 256;

struct Args {
    const int* x; const float* hd; const float* enc; const float* h0; const float* c0;
    const float* emb; const float* w_ih1; const float* w_hh1; const float* b_ih1;
    const float* b_hh1; const float* w_ih; const float* b_ih; const float* b_hh;
    const float* fc_w; const float* fc_b;
    float *m_part, *l_part, *acc_part, *inp_t, *zA, *zB, *P, *out, *out_h, *out_c;
};

// ---------------------------------------------------------------------------
// Phase 1: fused scores + online-softmax partials (enc read exactly once).
// One wave per (b, 32-key chunk); 2 keys in flight (kb = lane>>5), 32 lanes
// cover 512 dims as 4 float4 slices. ~75 VGPR -> fits 2-blocks/CU residency.
// ---------------------------------------------------------------------------
__device__ __forceinline__ void attn_phase(const Args& a)
{
    const int lane = threadIdx.x & 63;
    const int g = lane & 31, kb = lane >> 5;
    const int wgid = blockIdx.x * (BLK / 64) + (threadIdx.x >> 6);

    for (int u = wgid; u < B * NCHUNK; u += GRID * (BLK / 64)) {
        const int b = u >> 6, chunk = u & 63, s0 = chunk * 32;
        const float* hb = a.hd + (size_t)b * H;
        float4 hF[4];
#pragma unroll
        for (int j = 0; j < 4; ++j) hF[j] = *(const float4*)(hb + 128 * j + g * 4);
        const float* eb = a.enc + (size_t)b * S * H;

        float m = -1e30f, l = 0.f;
        float4 acc[4];
#pragma unroll
        for (int j = 0; j < 4; ++j) acc[j] = make_float4(0.f, 0.f, 0.f, 0.f);

        for (int it = 0; it < 16; ++it) {
            const float* kp = eb + (size_t)(s0 + it * 2 + kb) * H + g * 4;
            float4 e[4];
#pragma unroll
            for (int j = 0; j < 4; ++j) e[j] = *(const float4*)(kp + 128 * j);

            float p = 0.f;
#pragma unroll
            for (int j = 0; j < 4; ++j)
                p += e[j].x * hF[j].x + e[j].y * hF[j].y
                   + e[j].z * hF[j].z + e[j].w * hF[j].w;
            p += __shfl_xor(p, 1, 64);  p += __shfl_xor(p, 2, 64);
            p += __shfl_xor(p, 4, 64);  p += __shfl_xor(p, 8, 64);
            p += __shfl_xor(p, 16, 64);                 // per-key score, 32-lane uniform
            float bm = fmaxf(p, __shfl_xor(p, 32, 64)); // wave-uniform batch max

            if (bm <= m) {
                float w = __expf(p - m);
                float ws = w + __shfl_xor(w, 32, 64);
                l += ws;
#pragma unroll
                for (int j = 0; j < 4; ++j) {
                    acc[j].x += w * e[j].x; acc[j].y += w * e[j].y;
                    acc[j].z += w * e[j].z; acc[j].w += w * e[j].w;
                }
            } else {
                float sc = __expf(m - bm); m = bm;
                float w = __expf(p - bm);
                float ws = w + __shfl_xor(w, 32, 64);
                l = l * sc + ws;
#pragma unroll
                for (int j = 0; j < 4; ++j) {
                    acc[j].x = acc[j].x * sc + w * e[j].x;
                    acc[j].y = acc[j].y * sc + w * e[j].y;
                    acc[j].z = acc[j].z * sc + w * e[j].z;
                    acc[j].w = acc[j].w * sc + w * e[j].w;
                }
            }
        }
        float* af = (float*)acc;
#pragma unroll
        for (int q = 0; q < 16; ++q) af[q] += __shfl_xor(af[q], 32, 64);

        const int base = b * NCHUNK + chunk;
        if (lane == 0) { a.m_part[base] = m; a.l_part[base] = l; }
        float* ap = a.acc_part + (size_t)base * H;
        if (kb == 0) {
#pragma unroll
            for (int j = 0; j < 4; ++j) *(float4*)(ap + 128 * j + g * 4) = acc[j];
        }
    }
}

// ---------------------------------------------------------------------------
// Phase 2: combine partials -> ctx; embedding gather; transposed LSTM input
// inp_t[k][b]: [0,256)=xe, [256,768)=ctx, [768,1280)=h0.  512 blocks:
// block = (b, part), part owns 64 ctx dims; 4 threads share one dim.
// ---------------------------------------------------------------------------
__device__ __forceinline__ void combine_phase(const Args& a)
{
    const int b = blockIdx.x >> 3, part = blockIdx.x & 7, t = threadIdx.x;
    float M = -1e30f;
    for (int i = 0; i < NCHUNK; ++i) M = fmaxf(M, a.m_part[b * NCHUNK + i]);
    float L = 0.f;
    for (int i = 0; i < NCHUNK; ++i)
        L += a.l_part[b * NCHUNK + i] * __expf(a.m_part[b * NCHUNK + i] - M);
    const float invL = 1.f / L;

    const int d = part * 64 + (t >> 2), sub = t & 3;
    float s = 0.f;
    for (int i = sub; i < NCHUNK; i += 4)
        s += __expf(a.m_part[b * NCHUNK + i] - M) *
             a.acc_part[((size_t)(b * NCHUNK + i)) * H + d];
    s += __shfl_xor(s, 1, 64);
    s += __shfl_xor(s, 2, 64);
    if (sub == 0) a.inp_t[(E + d) * B + b] = s * invL;

    if (part == 0) a.inp_t[t * B + b] = a.emb[(size_t)a.x[b] * E + t];
    if (part == 2 || part == 3) {
        int d2 = (part - 2) * 256 + t;
        a.inp_t[(E + H + d2) * B + b] = a.h0[b * H + d2];
    }
}

// ---------------------------------------------------------------------------
// Tiled fp32 GEMM phase: C[M][64] = A[M][K] * X[K][64]. 256 thr, tile 64x64,
// BK=32, per-thread 4x4. A staged transposed [32][68] (ds_read_b128 frags),
// X staged [32][64]. Grid-stride over (m_tile, k_chunk) units.
// WMODE 0: split-K partial P[ck][M][64]; WMODE 1: final [b][ldc] + bias.
// ---------------------------------------------------------------------------
template<int WMODE>
__device__ __forceinline__ void gemm_phase(
    const float* __restrict__ A1, int lda1, int nck1,
    const float* __restrict__ A2, int lda2,
    const float* __restrict__ X, float* __restrict__ outp,
    const float* __restrict__ bias,
    int m_tiles, int M, int KC, int ldc, int units, float* sm)
{
    float (*As)[68] = (float(*)[68])sm;
    float (*Xs)[64] = (float(*)[64])(sm + 32 * 68);
    const int t = threadIdx.x;
    const int tx = t & 15, ty = t >> 4;

    for (int unit = blockIdx.x; unit < units; unit += GRID) {
        const int mt = unit % m_tiles, ck = unit / m_tiles;
        const float* A; int lda, kA0;
        if (ck < nck1) { A = A1; lda = lda1; kA0 = ck * KC; }
        else           { A = A2; lda = lda2; kA0 = ck * KC - nck1 * KC; }
        const int kX0 = ck * KC, m_base = mt * 64;

        float acc[4][4];
#pragma unroll
        for (int i = 0; i < 4; ++i)
#pragma unroll
            for (int j = 0; j < 4; ++j) acc[i][j] = 0.f;

        for (int k0 = 0; k0 < KC; k0 += 32) {
#pragma unroll
            for (int q = 0; q < 2; ++q) {       // X tile: 512 float4
                int f4 = t + q * 256, k = f4 >> 4, c = (f4 & 15) * 4;
                *(float4*)&Xs[k][c] =
                    *(const float4*)&X[(size_t)(kX0 + k0 + k) * 64 + c];
            }
#pragma unroll
            for (int rr = 0; rr < 2; ++rr) {    // A tile transposed
                int row = (t >> 3) + rr * 32, kq = (t & 7) * 4;
                float4 v = *(const float4*)&A[(size_t)(m_base + row) * lda + kA0 + k0 + kq];
                As[kq + 0][row] = v.x; As[kq + 1][row] = v.y;
                As[kq + 2][row] = v.z; As[kq + 3][row] = v.w;
            }
            __syncthreads();
#pragma unroll 8
            for (int k = 0; k < 32; ++k) {
                float4 av = *(const float4*)&As[k][ty * 4];
                float4 xv = *(const float4*)&Xs[k][tx * 4];
                float aa[4] = {av.x, av.y, av.z, av.w};
                float xx[4] = {xv.x, xv.y, xv.z, xv.w};
#pragma unroll
                for (int i = 0; i < 4; ++i)
#pragma unroll
                    for (int j = 0; j < 4; ++j) acc[i][j] += aa[i] * xx[j];
            }
            __syncthreads();
        }

        if constexpr (WMODE == 0) {
            float* P = outp + (size_t)ck * M * 64;
#pragma unroll
            for (int i = 0; i < 4; ++i)
                *(float4*)&P[(size_t)(m_base + ty * 4 + i) * 64 + tx * 4] =
                    make_float4(acc[i][0], acc[i][1], acc[i][2], acc[i][3]);
        } else {
#pragma unroll
            for (int j = 0; j < 4; ++j) {
                int b = tx * 4 + j;
                int v0 = m_base + ty * 4;
                float4 v;
                v.x = acc[0][j] + bias[v0 + 0];
                v.y = acc[1][j] + bias[v0 + 1];
                v.z = acc[2][j] + bias[v0 + 2];
                v.w = acc[3][j] + bias[v0 + 3];
                *(float4*)&outp[(size_t)b * ldc + v0] = v;
            }
        }
    }
}

// ---------------------------------------------------------------------------
// LSTM gate activation: sum split-K partials + biases, apply nonlinearity.
// ---------------------------------------------------------------------------
__device__ __forceinline__ void act_phase(
    const float* __restrict__ P, int nck,
    const float* __restrict__ b_ih, const float* __restrict__ b_hh,
    const float* __restrict__ c_prev, float* __restrict__ h_t,
    float* __restrict__ out_h, float* __restrict__ out_c)
{
    if (blockIdx.x >= 128) return;
    int idx = blockIdx.x * BLK + threadIdx.x;   // 32768 = H*B
    int b = idx & 63, j = idx >> 6;
    float g[4];
#pragma unroll
    for (int gg = 0; gg < 4; ++gg) {
        int row = j + 512 * gg;
        float s = b_ih[row] + b_hh[row];
        for (int c = 0; c < nck; ++c)
            s += P[((size_t)c * 2048 + row) * 64 + b];
        g[gg] = s;
    }
    float iv = 1.f / (1.f + __expf(-g[0]));
    float fv = 1.f / (1.f + __expf(-g[1]));
    float gv = tanhf(g[2]);
    float ov = 1.f / (1.f + __expf(-g[3]));
    float cp = c_prev ? c_prev[b * H + j] : 0.f;
    float c2 = fv * cp + iv * gv;
    float hv = ov * tanhf(c2);
    h_t[j * B + b] = hv;
    if (out_h) { out_h[b * H + j] = hv; out_c[b * H + j] = c2; }
}

// ---------------------------------------------------------------------------
__global__ __launch_bounds__(BLK, 2) void mega_kernel(Args a)
{
    cg::grid_group grid = cg::this_grid();
    __shared__ float sm[32 * 68 + 32 * 64];   // 16.9 KB

    attn_phase(a);
    __threadfence(); grid.sync();

    combine_phase(a);
    __threadfence(); grid.sync();

    // LSTM layer 1: K = 1280 (w_ih1 768 | w_hh1 512), KC=64 -> 20 chunks
    gemm_phase<0>(a.w_ih1, 768, 12, a.w_hh1, 512, a.inp_t, a.P, nullptr,
                  32, 2048, 64, 0, 640, sm);
    __threadfence(); grid.sync();
    act_phase(a.P, 20, a.b_ih1, a.b_hh1, a.c0, a.zA, nullptr, nullptr);
    __threadfence(); grid.sync();

    // LSTM layers 2-4 (zero h/c: only w_ih), K=512, KC=32 -> 16 chunks
    gemm_phase<0>(a.w_ih + 0 * (size_t)2048 * H, 512, 16, nullptr, 0, a.zA,
                  a.P, nullptr, 32, 2048, 32, 0, 512, sm);
    __threadfence(); grid.sync();
    act_phase(a.P, 16, a.b_ih + 0 * 2048, a.b_hh + 0 * 2048, nullptr, a.zB,
              nullptr, nullptr);
    __threadfence(); grid.sync();

    gemm_phase<0>(a.w_ih + 1 * (size_t)2048 * H, 512, 16, nullptr, 0, a.zB,
                  a.P, nullptr, 32, 2048, 32, 0, 512, sm);
    __threadfence(); grid.sync();
    act_phase(a.P, 16, a.b_ih + 1 * 2048, a.b_hh + 1 * 2048, nullptr, a.zA,
              nullptr, nullptr);
    __threadfence(); grid.sync();

    gemm_phase<0>(a.w_ih + 2 * (size_t)2048 * H, 512, 16, nullptr, 0, a.zA,
                  a.P, nullptr, 32, 2048, 32, 0, 512, sm);
    __threadfence(); grid.sync();
    act_phase(a.P, 16, a.b_ih + 2 * 2048, a.b_hh + 2 * 2048, nullptr, a.zB,
              a.out_h, a.out_c);
    __threadfence(); grid.sync();

    // fc: logits = zB^T @ fc_w^T + fc_b, 500 tiles, full K
    gemm_phase<1>(a.fc_w, 512, 1, nullptr, 0, a.zB, a.out, a.fc_b,
                  500, 32000, 512, V, 500, sm);
}

// ---------------------------------------------------------------------------
extern "C" void kernel_launch(void* const* d_in, const int* in_sizes, int n_in,
                              void* d_out, int out_size, void* d_ws, size_t ws_size,
                              hipStream_t stream)
{
    float* ws = (float*)d_ws;

    Args a;
    a.x     = (const int*)d_in[0];
    a.hd    = (const float*)d_in[1];
    a.enc   = (const float*)d_in[2];
    a.h0    = (const float*)d_in[3];
    a.c0    = (const float*)d_in[4];
    a.emb   = (const float*)d_in[5];
    a.w_ih1 = (const float*)d_in[6];
    a.w_hh1 = (const float*)d_in[7];
    a.b_ih1 = (const float*)d_in[8];
    a.b_hh1 = (const float*)d_in[9];
    a.w_ih  = (const float*)d_in[10];
    // d_in[11] = w_hh: multiplied by zero hidden state in layers 2-4 -> skipped
    a.b_ih  = (const float*)d_in[12];
    a.b_hh  = (const float*)d_in[13];
    a.fc_w  = (const float*)d_in[14];
    a.fc_b  = (const float*)d_in[15];

    a.m_part   = ws;                                   // 4096
    a.l_part   = ws + 4096;                            // 4096
    a.acc_part = ws + 8192;                            // 64*64*512
    a.inp_t    = a.acc_part + (size_t)B * NCHUNK * H;  // 1280*64
    a.zA       = a.inp_t + 1280 * B;
    a.zB       = a.zA + H * B;
    a.P        = a.zB + H * B;                         // 20*2048*64

    a.out   = (float*)d_out;
    a.out_h = a.out + (size_t)B * V;
    a.out_c = a.out_h + (size_t)B * H;

    void* kargs[] = { (void*)&a };
    hipLaunchCooperativeKernel((void*)mega_kernel, dim3(GRID), dim3(BLK),
                               kargs, 0, stream);
}

// Round 5
// 193.335 us; speedup vs baseline: 6.4723x; 6.4723x over previous
//
#include <hip/hip_runtime.h>
#include <cstdint>
#include <cstddef>

// Problem constants
constexpr int B = 64, S = 2048, H = 512, E = 256, V = 32000;
constexpr int NCHUNK = 32;   // attention: 32 chunks of 64 keys per batch

// ---------------------------------------------------------------------------
// Kernel 1: fused scores + online-softmax partials (enc read exactly once).
// One wave per (b, 64-key chunk); lane covers 8 of 512 dims (2 float4 slices).
// (proven round-2 version, unchanged)
// ---------------------------------------------------------------------------
__global__ __launch_bounds__(256) void attn_part_kernel(
    const float* __restrict__ hd, const float* __restrict__ enc,
    float* __restrict__ m_part, float* __restrict__ l_part,
    float* __restrict__ acc_part)
{
    int b = blockIdx.x >> 3;
    int wave = threadIdx.x >> 6, lane = threadIdx.x & 63;
    int chunk = ((blockIdx.x & 7) << 2) + wave;
    int s0 = chunk * 64;

    const float4* hv = (const float4*)(hd + (size_t)b * H);
    float4 h0 = hv[lane], h1 = hv[64 + lane];
    const float4* ev = (const float4*)(enc + (size_t)b * S * H) + (size_t)s0 * (H / 4);

    float4 e0 = ev[lane], e1 = ev[64 + lane];
    float p = e0.x * h0.x + e0.y * h0.y + e0.z * h0.z + e0.w * h0.w
            + e1.x * h1.x + e1.y * h1.y + e1.z * h1.z + e1.w * h1.w;
#pragma unroll
    for (int off = 32; off; off >>= 1) p += __shfl_xor(p, off, 64);
    float m = p, l = 1.f;
    float4 a0 = e0, a1 = e1;

    for (int s = 1; s < 64; ++s) {
        const float4* row = ev + (size_t)s * (H / 4);
        e0 = row[lane]; e1 = row[64 + lane];
        p = e0.x * h0.x + e0.y * h0.y + e0.z * h0.z + e0.w * h0.w
          + e1.x * h1.x + e1.y * h1.y + e1.z * h1.z + e1.w * h1.w;
#pragma unroll
        for (int off = 32; off; off >>= 1) p += __shfl_xor(p, off, 64);
        if (p <= m) {
            float w = __expf(p - m);
            l += w;
            a0.x += w * e0.x; a0.y += w * e0.y; a0.z += w * e0.z; a0.w += w * e0.w;
            a1.x += w * e1.x; a1.y += w * e1.y; a1.z += w * e1.z; a1.w += w * e1.w;
        } else {
            float sc = __expf(m - p);
            m = p;
            l = l * sc + 1.f;
            a0.x = a0.x * sc + e0.x; a0.y = a0.y * sc + e0.y;
            a0.z = a0.z * sc + e0.z; a0.w = a0.w * sc + e0.w;
            a1.x = a1.x * sc + e1.x; a1.y = a1.y * sc + e1.y;
            a1.z = a1.z * sc + e1.z; a1.w = a1.w * sc + e1.w;
        }
    }

    int base = b * NCHUNK + chunk;
    if (lane == 0) { m_part[base] = m; l_part[base] = l; }
    float4* ap = (float4*)(acc_part + (size_t)base * H);
    ap[lane] = a0; ap[64 + lane] = a1;
}

// ---------------------------------------------------------------------------
// Kernel 2: combine partials -> ctx; embedding gather; transposed LSTM input
// inp_t[k][b]: [0,256)=xe, [256,768)=ctx, [768,1280)=h0. (round-2, unchanged)
// ---------------------------------------------------------------------------
__global__ __launch_bounds__(256) void combine_kernel(
    const float* __restrict__ m_part, const float* __restrict__ l_part,
    const float* __restrict__ acc_part, const int* __restrict__ x,
    const float* __restrict__ emb, const float* __restrict__ h0,
    float* __restrict__ inp_t)
{
    int b = blockIdx.x, t = threadIdx.x;
    float M = -1e30f;
    for (int i = 0; i < NCHUNK; ++i) M = fmaxf(M, m_part[b * NCHUNK + i]);
    float L = 0.f;
    for (int i = 0; i < NCHUNK; ++i)
        L += l_part[b * NCHUNK + i] * __expf(m_part[b * NCHUNK + i] - M);
    float invL = 1.f / L;

    for (int d = t; d < H; d += 256) {
        float s = 0.f;
        for (int i = 0; i < NCHUNK; ++i)
            s += __expf(m_part[b * NCHUNK + i] - M) *
                 acc_part[((size_t)(b * NCHUNK + i)) * H + d];
        inp_t[(E + d) * B + b] = s * invL;
    }
    inp_t[t * B + b] = emb[(size_t)x[b] * E + t];
    for (int d = t; d < H; d += 256)
        inp_t[(E + H + d) * B + b] = h0[b * H + d];
}

// ---------------------------------------------------------------------------
// Kernel 3: FULLY-FUSED LSTM layer. Block = 4 hidden units j (x 4 gates = 16
// A-rows). Intra-block split-K: wave-quarter kq owns K/4; per k: 2x
// ds_read_b128 -> 16 FMA. LDS partial-reduce, then gate activation epilogue.
// Grid 128 blocks covers j=0..511. Kills split-K P traffic + act kernels.
// A-rows for block j0: row(i_local) = j0 + (i_local&3) + 512*(i_local>>2).
// Supports concatenated K (layer 1: A1 = w_ih1 (k1len=768) | A2 = w_hh1).
// ---------------------------------------------------------------------------
__global__ __launch_bounds__(256) void lstm_fused_kernel(
    const float* __restrict__ A1, int lda1, int k1len,
    const float* __restrict__ A2, int lda2, int KT,
    const float* __restrict__ X,
    const float* __restrict__ b_ih, const float* __restrict__ b_hh,
    const float* __restrict__ c_prev,
    float* __restrict__ h_t, float* __restrict__ out_h, float* __restrict__ out_c)
{
    __shared__ float sm[4 * 32 * 20 + 4 * 32 * 64];   // As | Xs  (42.5 KB)
    float (*As)[32][20] = (float(*)[32][20])sm;
    float (*Xs)[32][64] = (float(*)[32][64])(sm + 4 * 32 * 20);
    float (*Ps)[16][64] = (float(*)[16][64])(sm + 4 * 32 * 20); // aliases Xs

    const int t = threadIdx.x;
    const int j0 = blockIdx.x * 4;
    const int QK = KT >> 2;          // K per quarter
    const int nIter = QK >> 5;       // 32-k tiles per quarter

    const int kq = t >> 6, r = t & 63, ty = r >> 4, tx = r & 15;

    float acc[4][4];
#pragma unroll
    for (int i = 0; i < 4; ++i)
#pragma unroll
        for (int j = 0; j < 4; ++j) acc[i][j] = 0.f;

    for (int it = 0; it < nIter; ++it) {
        // stage A: 16 rows x 128 k (32 per quarter), transposed into As
#pragma unroll
        for (int q = 0; q < 2; ++q) {
            int p = t + q * 256;             // 0..511 float4 chunks
            int il = p >> 5, c = p & 31;
            int akq = c >> 3, k4 = (c & 7) * 4;
            int gk = akq * QK + it * 32 + k4;
            int grow = j0 + (il & 3) + 512 * (il >> 2);
            const float* src = (gk < k1len)
                ? A1 + (size_t)grow * lda1 + gk
                : A2 + (size_t)grow * lda2 + (gk - k1len);
            float4 v = *(const float4*)src;
            As[akq][k4 + 0][il] = v.x; As[akq][k4 + 1][il] = v.y;
            As[akq][k4 + 2][il] = v.z; As[akq][k4 + 3][il] = v.w;
        }
        // stage X: 128 k x 64 b
#pragma unroll
        for (int q = 0; q < 8; ++q) {
            int p = t + q * 256;             // 0..2047 float4 chunks
            int kk_all = p >> 4, col = (p & 15) * 4;
            int xkq = kk_all >> 5, kk = kk_all & 31;
            int gk = xkq * QK + it * 32 + kk;
            *(float4*)&Xs[xkq][kk][col] = *(const float4*)&X[(size_t)gk * 64 + col];
        }
        __syncthreads();

#pragma unroll 8
        for (int kk = 0; kk < 32; ++kk) {
            float4 av = *(const float4*)&As[kq][kk][ty * 4];
            float4 xv = *(const float4*)&Xs[kq][kk][tx * 4];
            float aa[4] = {av.x, av.y, av.z, av.w};
            float xx[4] = {xv.x, xv.y, xv.z, xv.w};
#pragma unroll
            for (int i = 0; i < 4; ++i)
#pragma unroll
                for (int j = 0; j < 4; ++j) acc[i][j] += aa[i] * xx[j];
        }
        __syncthreads();
    }

    // store per-quarter partials (into Xs memory; all reads done)
#pragma unroll
    for (int i = 0; i < 4; ++i)
        *(float4*)&Ps[kq][ty * 4 + i][tx * 4] =
            make_float4(acc[i][0], acc[i][1], acc[i][2], acc[i][3]);
    __syncthreads();

    // reduce 4 quarters -> Ps[0]
    for (int idx = t; idx < 16 * 64; idx += 256) {
        int row = idx >> 6, b = idx & 63;
        Ps[0][row][b] = Ps[0][row][b] + Ps[1][row][b] + Ps[2][row][b] + Ps[3][row][b];
    }
    __syncthreads();

    // gate activation: t -> (jj = t>>6, b = t&63)
    {
        int jj = t >> 6, b = t & 63;
        int j = j0 + jj;
        float gi = Ps[0][jj][b]      + b_ih[j]        + b_hh[j];
        float gf = Ps[0][4 + jj][b]  + b_ih[j + 512]  + b_hh[j + 512];
        float gg = Ps[0][8 + jj][b]  + b_ih[j + 1024] + b_hh[j + 1024];
        float go = Ps[0][12 + jj][b] + b_ih[j + 1536] + b_hh[j + 1536];
        float iv = 1.f / (1.f + __expf(-gi));
        float fv = 1.f / (1.f + __expf(-gf));
        float gv = tanhf(gg);
        float ov = 1.f / (1.f + __expf(-go));
        float cp = c_prev ? c_prev[b * H + j] : 0.f;
        float c2 = fv * cp + iv * gv;
        float hv = ov * tanhf(c2);
        h_t[j * B + b] = hv;                    // transposed for next consumer
        if (out_h) { out_h[b * H + j] = hv; out_c[b * H + j] = c2; }
    }
}

// ---------------------------------------------------------------------------
// Kernel 4: fc logits GEMM (round-2 proven config: BM=128, TM=8, TN=2,
// 512 threads, full K, bias epilogue, direct [b][V] writes).
// ---------------------------------------------------------------------------
__global__ __launch_bounds__(512) void fc_gemm_kernel(
    const float* __restrict__ A, const float* __restrict__ X,
    float* __restrict__ outp, const float* __restrict__ bias)
{
    constexpr int BM = 128, TM = 8;
    __shared__ float As[32][BM + 4];
    __shared__ float Xs[32][64];

    int t = threadIdx.x;
    int tx = t & 31, ty = t >> 5;
    int m_base = blockIdx.x * BM;

    float acc[TM][2];
#pragma unroll
    for (int i = 0; i < TM; ++i) { acc[i][0] = 0.f; acc[i][1] = 0.f; }

    for (int k0 = 0; k0 < 512; k0 += 32) {
        {
            int kx = t >> 4, bq = t & 15;
            *(float4*)&Xs[kx][bq * 4] =
                *(const float4*)&X[(size_t)(k0 + kx) * 64 + bq * 4];
        }
        {
            int kq = t & 7, rr = t >> 3;   // rr in 0..63
#pragma unroll
            for (int rep = 0; rep < 2; ++rep) {
                int row = rr + rep * 64;
                float4 v = *(const float4*)&A[(size_t)(m_base + row) * 512 + k0 + kq * 4];
                As[kq * 4 + 0][row] = v.x;
                As[kq * 4 + 1][row] = v.y;
                As[kq * 4 + 2][row] = v.z;
                As[kq * 4 + 3][row] = v.w;
            }
        }
        __syncthreads();

#pragma unroll 4
        for (int k = 0; k < 32; ++k) {
            float a[TM];
            *(float4*)&a[0] = *(const float4*)&As[k][ty * TM];
            *(float4*)&a[4] = *(const float4*)&As[k][ty * TM + 4];
            float2 xv = *(const float2*)&Xs[k][tx * 2];
#pragma unroll
            for (int i = 0; i < TM; ++i) {
                acc[i][0] += a[i] * xv.x;
                acc[i][1] += a[i] * xv.y;
            }
        }
        __syncthreads();
    }

#pragma unroll
    for (int j = 0; j < 2; ++j) {
        int b = tx * 2 + j;
#pragma unroll
        for (int i = 0; i < TM; i += 4) {
            int v0 = m_base + ty * TM + i;
            float4 v;
            v.x = acc[i + 0][j] + bias[v0 + 0];
            v.y = acc[i + 1][j] + bias[v0 + 1];
            v.z = acc[i + 2][j] + bias[v0 + 2];
            v.w = acc[i + 3][j] + bias[v0 + 3];
            *(float4*)&outp[(size_t)b * V + v0] = v;
        }
    }
}

// ---------------------------------------------------------------------------
extern "C" void kernel_launch(void* const* d_in, const int* in_sizes, int n_in,
                              void* d_out, int out_size, void* d_ws, size_t ws_size,
                              hipStream_t stream)
{
    const int*   x     = (const int*)d_in[0];
    const float* hdec  = (const float*)d_in[1];
    const float* enc   = (const float*)d_in[2];
    const float* h0    = (const float*)d_in[3];
    const float* c0    = (const float*)d_in[4];
    const float* emb   = (const float*)d_in[5];
    const float* w_ih1 = (const float*)d_in[6];
    const float* w_hh1 = (const float*)d_in[7];
    const float* b_ih1 = (const float*)d_in[8];
    const float* b_hh1 = (const float*)d_in[9];
    const float* w_ih  = (const float*)d_in[10];
    // d_in[11] = w_hh: multiplied by zero hidden state in layers 2-4 -> skipped
    const float* b_ih  = (const float*)d_in[12];
    const float* b_hh  = (const float*)d_in[13];
    const float* fc_w  = (const float*)d_in[14];
    const float* fc_b  = (const float*)d_in[15];

    float* out = (float*)d_out;
    float* ws  = (float*)d_ws;

    // ws layout (floats)
    float* m_part   = ws;                                // 2048
    float* l_part   = ws + 2048;                         // 2048
    float* acc_part = ws + 4096;                         // 64*32*512
    float* inp_t    = acc_part + (size_t)B * NCHUNK * H; // 1280*64
    float* zA       = inp_t + 1280 * B;                  // 512*64
    float* zB       = zA + H * B;                        // 512*64

    float* out_h = out + (size_t)B * V;
    float* out_c = out_h + (size_t)B * H;

    // 1) attention (enc read once, 268 MB)
    attn_part_kernel<<<512, 256, 0, stream>>>(hdec, enc, m_part, l_part, acc_part);
    combine_kernel<<<64, 256, 0, stream>>>(m_part, l_part, acc_part, x, emb, h0, inp_t);

    // 2) LSTM layer 1: K = 768 (w_ih1) | 512 (w_hh1) = 1280, real c0
    lstm_fused_kernel<<<128, 256, 0, stream>>>(
        w_ih1, 768, 768, w_hh1, 512, 1280, inp_t,
        b_ih1, b_hh1, c0, zA, nullptr, nullptr);

    // 3) LSTM layers 2-4 (zero h/c: only w_ih contributes), K = 512
    lstm_fused_kernel<<<128, 256, 0, stream>>>(
        w_ih + 0 * (size_t)2048 * H, 512, 512, nullptr, 0, 512, zA,
        b_ih + 0 * 2048, b_hh + 0 * 2048, nullptr, zB, nullptr, nullptr);
    lstm_fused_kernel<<<128, 256, 0, stream>>>(
        w_ih + 1 * (size_t)2048 * H, 512, 512, nullptr, 0, 512, zB,
        b_ih + 1 * 2048, b_hh + 1 * 2048, nullptr, zA, nullptr, nullptr);
    lstm_fused_kernel<<<128, 256, 0, stream>>>(
        w_ih + 2 * (size_t)2048 * H, 512, 512, nullptr, 0, 512, zA,
        b_ih + 2 * 2048, b_hh + 2 * 2048, nullptr, zB, out_h, out_c);

    // 4) logits = zB^T @ fc_w^T + fc_b
    fc_gemm_kernel<<<250, 512, 0, stream>>>(fc_w, zB, out, fc_b);
}